// Round 3
// baseline (2457.723 us; speedup 1.0000x reference)
//
#include <hip/hip_runtime.h>
#include <math.h>

typedef __attribute__((ext_vector_type(8))) short bf16x8;
typedef __attribute__((ext_vector_type(4))) float f32x4;
typedef __attribute__((ext_vector_type(4))) unsigned short us4;

__device__ inline unsigned short f2bf(float f){
  unsigned u = __float_as_uint(f);
  u += 0x7fff + ((u>>16)&1);
  return (unsigned short)(u>>16);
}

__device__ __forceinline__ void gload16(const void* g, void* l){
  __builtin_amdgcn_global_load_lds(
      (const __attribute__((address_space(1))) unsigned int*)g,
      (__attribute__((address_space(3))) unsigned int*)l, 16, 0, 0);
}

// ---------- feat NCHW fp32 -> featT NHWC bf16 (padded width Wp=W+2) ----------
__global__ __launch_bounds__(256) void k_trans(const float* __restrict__ feat,
    unsigned short* __restrict__ ft, int H, int W, int Wp, int y_begin,
    int slot_base, int RBf)
{
  int t = threadIdx.x;
  int lane = t & 63, wv = t >> 6;
  int x = blockIdx.x*64 + lane;
  int y = y_begin + blockIdx.y;
  int b = blockIdx.z;
  int slot = slot_base + blockIdx.y;
  if (x >= W) return;
  const float* fb = feat + ((size_t)(b*256)*H + y)*W + x;
  unsigned short* dst = ft + (((size_t)b*RBf + slot)*Wp + x + 1)*256;
  #pragma unroll 4
  for (int i=0;i<16;i++){
    int c0 = wv*4 + i*16;
    float v0 = fb[(size_t)(c0+0)*H*W];
    float v1 = fb[(size_t)(c0+1)*H*W];
    float v2 = fb[(size_t)(c0+2)*H*W];
    float v3 = fb[(size_t)(c0+3)*H*W];
    us4 o = { f2bf(v0), f2bf(v1), f2bf(v2), f2bf(v3) };
    *(us4*)(dst + c0) = o;
  }
}

// ---------- zero helpers ----------
__global__ __launch_bounds__(256) void k_zrow(unsigned short* __restrict__ buf,
    long bStr, int Wp, int slot0, int nslots)
{
  long i = ((long)blockIdx.x*256 + threadIdx.x)*8;
  long per_b = (long)nslots*Wp*256;
  if (i >= 4*per_b) return;
  int b = (int)(i / per_b); long r = i % per_b;
  unsigned short* d = buf + (size_t)b*bStr + (size_t)slot0*Wp*256 + r;
  us4 z = {0,0,0,0};
  *(us4*)d = z; *(us4*)(d+4) = z;
}

__global__ __launch_bounds__(256) void k_zcol(unsigned short* __restrict__ buf,
    int Wp, int RB, int W)
{
  long i = ((long)blockIdx.x*256 + threadIdx.x)*8;
  long tot = (long)4*RB*2*256;
  if (i >= tot) return;
  long u = i/8; int q = (int)(u & 31); int side = (int)((u>>5)&1);
  long bs = u>>6; int slot = (int)(bs % RB); int b = (int)(bs / RB);
  unsigned short* d = buf + (((size_t)b*RB + slot)*Wp + (side? W+1 : 0))*256 + q*8;
  us4 z = {0,0,0,0};
  *(us4*)d = z; *(us4*)(d+4) = z;
}

// ---------- weight repacks (unchanged layouts from round 2) ----------
__global__ __launch_bounds__(256) void k_repack_conv(const float* __restrict__ w,
    const float* __restrict__ g, const float* __restrict__ v,
    unsigned short* __restrict__ wf)
{
  int t = blockIdx.x*256 + threadIdx.x;
  if (t >= 4*256*256) return;
  int ci = t & 255, co = (t>>8) & 255, l = t>>16;
  float s = g[l*256+co] * rsqrtf(v[l*256+co] + 1e-5f);
  const float* wp = w + (size_t)t*9;
  int cb = co>>4, kc = ci>>5;
  int lane = ((ci>>3)&3)*16 + (co&15);
  int e = ci&7;
  size_t base = (((size_t)(l*16+cb)*8 + kc)*9)*512 + (size_t)lane*8 + e;
  #pragma unroll
  for (int tap=0;tap<9;tap++)
    wf[base + (size_t)tap*512] = f2bf(wp[tap]*s);
}

__global__ __launch_bounds__(256) void k_repack_adapt(const float* __restrict__ w,
    unsigned short* __restrict__ wf)
{
  int t = blockIdx.x*256 + threadIdx.x;
  if (t >= 4*256*32) return;
  int o = t & 31, co = (t>>5)&255, l = t>>13;
  int ci0 = o*8;
  const float* wp = w + ((size_t)(l*256+co)*256 + ci0);
  int cb = co>>4, kc = o>>2, lane = (o&3)*16 + (co&15);
  unsigned short* dst = wf + (((size_t)(l*16+cb)*8 + kc)*64 + lane)*8;
  unsigned short tmp[8];
  #pragma unroll
  for (int e=0;e<8;e++) tmp[e] = f2bf(wp[e]);
  *(us4*)dst = *(us4*)tmp; *(us4*)(dst+4) = *(us4*)(tmp+4);
}

__global__ __launch_bounds__(192) void k_repack_pred(const float* __restrict__ w,
    unsigned short* __restrict__ wf)
{
  int t = blockIdx.x*192 + threadIdx.x;
  if (t >= 4*48*32) return;
  int o = t & 31, co = (t>>5)%48, l = t/1536;
  int ci0 = o*8, f = co>>4, kc = o>>2, lane = (o&3)*16 + (co&15);
  unsigned short* dst = wf + ((((size_t)l*8 + kc)*3 + f)*64 + lane)*8;
  #pragma unroll
  for (int e=0;e<8;e++){
    float val = (co<45) ? w[((size_t)(l*45+co)*256 + ci0 + e)] : 0.f;
    dst[e] = f2bf(val);
  }
}

__global__ __launch_bounds__(256) void k_bias(const float* __restrict__ b,
    const float* __restrict__ g, const float* __restrict__ be,
    const float* __restrict__ m, const float* __restrict__ v,
    float* __restrict__ out)
{
  int t = blockIdx.x*256 + threadIdx.x;
  if (t >= 1024) return;
  float s = g[t]*rsqrtf(v[t]+1e-5f);
  out[t] = (b[t]-m[t])*s + be[t];
}

// ---------- pipelined MFMA conv: 2 output rows/block, gload_lds staging ----------
template<int TAPS, bool RELU>
__global__ __launch_bounds__(256, 2) void k_conv2r(
    const unsigned short* __restrict__ in, const unsigned short* __restrict__ wf,
    const float* __restrict__ bias, unsigned short* __restrict__ outb,
    int W, int Wp, int y_begin, int n_rows, int in_row0, int RBin,
    int out_row0, int RBout)
{
  constexpr int PAD  = (TAPS==9) ? 1 : 0;
  constexpr int KYW  = (TAPS==9) ? 4 : 2;     // staged input rows
  constexpr int NCH  = (TAPS==9) ? 17 : 8;    // 1KB gload chunks per tile
  constexpr int BUFB = NCH*1024;
  constexpr int K2   = (TAPS==9) ? 4 : 2;     // per-wave loads per stage
  __shared__ __align__(128) char lds[2*BUFB];

  int tid = threadIdx.x;
  int lane = tid & 63, w = tid >> 6;
  int l15 = lane & 15, g4 = lane >> 4;
  int x0 = blockIdx.x * 64;
  int y0 = y_begin + 2*blockIdx.y;
  int b  = blockIdx.z;

  size_t rowStr = (size_t)Wp * 256;
  const unsigned short* gb = in
      + ((size_t)b*RBin + (y0 - PAD - in_row0)) * rowStr
      + (size_t)(x0 + (TAPS==1 ? 1 : 0)) * 256;
  const unsigned short* wA = wf + (size_t)(w*4)*(8*TAPS*512) + (size_t)lane*8;

  // precomputed swizzled LDS read offsets; addr(ky) = v ^ (ky<<6)
  int v[(TAPS==9)?12:4];
  if constexpr (TAPS==9){
    #pragma unroll
    for (int kx=0;kx<3;kx++)
      #pragma unroll
      for (int pf=0;pf<4;pf++){
        int px = pf*16 + l15 + kx;
        int slot = g4 ^ ((px>>1)&3);
        v[kx*4+pf] = px*256 + slot*16 + (px&1)*64;
      }
  } else {
    #pragma unroll
    for (int pf=0;pf<4;pf++){
      int px = pf*16 + l15;
      int slot = g4 ^ ((px>>1)&3);
      v[pf] = px*128 + slot*16 + (px&1)*64;
    }
  }

  f32x4 acc0[4][4], acc1[4][4];
  #pragma unroll
  for (int i=0;i<4;i++)
    #pragma unroll
    for (int j=0;j<4;j++){
      acc0[i][j] = (f32x4){0.f,0.f,0.f,0.f};
      acc1[i][j] = (f32x4){0.f,0.f,0.f,0.f};
    }

  // stage: linear LDS dest, inverse-swizzled per-lane global source
  auto stage = [&](int kc, char* buf){
    #pragma unroll
    for (int i=0;i<(NCH+3)/4;i++){
      int c = w + 4*i;
      if (c < NCH){
        int s = c*64 + lane;
        int px  = s >> ((TAPS==9)?4:3);
        int kyp = (s>>2) & (KYW-1);
        int q   = s & 3;
        int kyd = kyp ^ (px & 1);
        int cis = q ^ ((px>>1) & 3);
        const unsigned short* g = gb + (size_t)kc*32 + (size_t)kyd*rowStr
                                + (size_t)(px*256 + cis*8);
        int ldsoff = __builtin_amdgcn_readfirstlane(c*1024);
        gload16(g, buf + ldsoff);
      }
    }
  };

  auto compute = [&](int kc, const char* cur){
    if constexpr (TAPS==9){
      #pragma unroll
      for (int kx=0;kx<3;kx++){
        bf16x8 Ba[4], Bb[4];
        #pragma unroll
        for (int pf=0;pf<4;pf++) Ba[pf] = *(const bf16x8*)(cur + v[kx*4+pf]);
        #pragma unroll
        for (int pf=0;pf<4;pf++) Bb[pf] = *(const bf16x8*)(cur + (v[kx*4+pf] ^ 64));
        // ty=0: rows 0,1
        {
          bf16x8 Af[4];
          #pragma unroll
          for (int cf=0;cf<4;cf++)
            Af[cf] = *(const bf16x8*)(wA + (size_t)cf*(8*TAPS*512) + (size_t)kc*(TAPS*512) + (size_t)kx*512);
          #pragma unroll
          for (int cf=0;cf<4;cf++)
            #pragma unroll
            for (int pf=0;pf<4;pf++){
              acc0[cf][pf] = __builtin_amdgcn_mfma_f32_16x16x32_bf16(Af[cf], Ba[pf], acc0[cf][pf], 0,0,0);
              acc1[cf][pf] = __builtin_amdgcn_mfma_f32_16x16x32_bf16(Af[cf], Bb[pf], acc1[cf][pf], 0,0,0);
            }
        }
        #pragma unroll
        for (int pf=0;pf<4;pf++) Ba[pf] = *(const bf16x8*)(cur + (v[kx*4+pf] ^ 128)); // ky2
        // ty=1: rows 1,2
        {
          bf16x8 Af[4];
          #pragma unroll
          for (int cf=0;cf<4;cf++)
            Af[cf] = *(const bf16x8*)(wA + (size_t)cf*(8*TAPS*512) + (size_t)kc*(TAPS*512) + (size_t)(3+kx)*512);
          #pragma unroll
          for (int cf=0;cf<4;cf++)
            #pragma unroll
            for (int pf=0;pf<4;pf++){
              acc0[cf][pf] = __builtin_amdgcn_mfma_f32_16x16x32_bf16(Af[cf], Bb[pf], acc0[cf][pf], 0,0,0);
              acc1[cf][pf] = __builtin_amdgcn_mfma_f32_16x16x32_bf16(Af[cf], Ba[pf], acc1[cf][pf], 0,0,0);
            }
        }
        #pragma unroll
        for (int pf=0;pf<4;pf++) Bb[pf] = *(const bf16x8*)(cur + (v[kx*4+pf] ^ 192)); // ky3
        // ty=2: rows 2,3
        {
          bf16x8 Af[4];
          #pragma unroll
          for (int cf=0;cf<4;cf++)
            Af[cf] = *(const bf16x8*)(wA + (size_t)cf*(8*TAPS*512) + (size_t)kc*(TAPS*512) + (size_t)(6+kx)*512);
          #pragma unroll
          for (int cf=0;cf<4;cf++)
            #pragma unroll
            for (int pf=0;pf<4;pf++){
              acc0[cf][pf] = __builtin_amdgcn_mfma_f32_16x16x32_bf16(Af[cf], Ba[pf], acc0[cf][pf], 0,0,0);
              acc1[cf][pf] = __builtin_amdgcn_mfma_f32_16x16x32_bf16(Af[cf], Bb[pf], acc1[cf][pf], 0,0,0);
            }
        }
      }
    } else {
      bf16x8 B0[4], B1[4];
      #pragma unroll
      for (int pf=0;pf<4;pf++) B0[pf] = *(const bf16x8*)(cur + v[pf]);
      #pragma unroll
      for (int pf=0;pf<4;pf++) B1[pf] = *(const bf16x8*)(cur + (v[pf] ^ 64));
      bf16x8 Af[4];
      #pragma unroll
      for (int cf=0;cf<4;cf++)
        Af[cf] = *(const bf16x8*)(wA + (size_t)cf*(8*TAPS*512) + (size_t)kc*(TAPS*512));
      #pragma unroll
      for (int cf=0;cf<4;cf++)
        #pragma unroll
        for (int pf=0;pf<4;pf++){
          acc0[cf][pf] = __builtin_amdgcn_mfma_f32_16x16x32_bf16(Af[cf], B0[pf], acc0[cf][pf], 0,0,0);
          acc1[cf][pf] = __builtin_amdgcn_mfma_f32_16x16x32_bf16(Af[cf], B1[pf], acc1[cf][pf], 0,0,0);
        }
    }
  };

  // prologue: 2 stages in flight
  stage(0, lds);
  stage(1, lds + BUFB);
  asm volatile("s_waitcnt vmcnt(%0)" :: "n"(K2) : "memory");
  __builtin_amdgcn_s_barrier();
  __builtin_amdgcn_sched_barrier(0);

#define KSTEP(KC, OFF, KW) \
  __builtin_amdgcn_s_setprio(1); \
  compute(KC, lds + (OFF)); \
  __builtin_amdgcn_s_setprio(0); \
  __builtin_amdgcn_sched_barrier(0); \
  __builtin_amdgcn_s_barrier(); \
  __builtin_amdgcn_sched_barrier(0); \
  if constexpr ((KC)+2 < 8) stage((KC)+2, lds + (OFF)); \
  asm volatile("s_waitcnt vmcnt(%0)" :: "n"(KW) : "memory"); \
  __builtin_amdgcn_s_barrier(); \
  __builtin_amdgcn_sched_barrier(0);

  KSTEP(0, 0, K2) KSTEP(1, BUFB, K2) KSTEP(2, 0, K2) KSTEP(3, BUFB, K2)
  KSTEP(4, 0, K2) KSTEP(5, BUFB, K2) KSTEP(6, 0, 0)
#undef KSTEP
  __builtin_amdgcn_s_setprio(1);
  compute(7, lds + BUFB);
  __builtin_amdgcn_s_setprio(0);

  // epilogue
  bool ok1 = (2*blockIdx.y + 1) < n_rows;
  int oslot = y0 - out_row0;
  #pragma unroll
  for (int cf=0;cf<4;cf++){
    int co0 = w*64 + cf*16 + g4*4;
    f32x4 bb = *(const f32x4*)(bias + co0);
    #pragma unroll
    for (int pf=0;pf<4;pf++){
      int x = x0 + pf*16 + l15;
      if (x < W){
        float v0 = acc0[cf][pf][0]+bb[0], v1 = acc0[cf][pf][1]+bb[1];
        float v2 = acc0[cf][pf][2]+bb[2], v3 = acc0[cf][pf][3]+bb[3];
        if (RELU){ v0=fmaxf(v0,0.f); v1=fmaxf(v1,0.f); v2=fmaxf(v2,0.f); v3=fmaxf(v3,0.f); }
        us4 o = { f2bf(v0), f2bf(v1), f2bf(v2), f2bf(v3) };
        *(us4*)(outb + (((size_t)b*RBout + oslot)*Wp + (x+1))*256 + co0) = o;
        if (ok1){
          float u0 = acc1[cf][pf][0]+bb[0], u1 = acc1[cf][pf][1]+bb[1];
          float u2 = acc1[cf][pf][2]+bb[2], u3 = acc1[cf][pf][3]+bb[3];
          if (RELU){ u0=fmaxf(u0,0.f); u1=fmaxf(u1,0.f); u2=fmaxf(u2,0.f); u3=fmaxf(u3,0.f); }
          us4 o1 = { f2bf(u0), f2bf(u1), f2bf(u2), f2bf(u3) };
          *(us4*)(outb + (((size_t)b*RBout + oslot + 1)*Wp + (x+1))*256 + co0) = o1;
        }
      }
    }
  }
}

// ---------- pred MFMA: NHWC bf16 -> sectioned NCHW fp32 out ----------
__global__ __launch_bounds__(256) void k_pred_mfma(
    const unsigned short* __restrict__ in, const unsigned short* __restrict__ wfP,
    const float* __restrict__ bp, float* __restrict__ outl,
    int H, int W, int Wp, int y_begin, int in_row0, int RBin)
{
  __shared__ __align__(16) unsigned short Xs[64][40];
  int tid = threadIdx.x;
  int lane = tid&63, w = tid>>6;
  int l15 = lane&15, g4 = lane>>4;
  int x0 = blockIdx.x*64;
  int y = y_begin + blockIdx.y;
  int b = blockIdx.z;
  int slot = y - in_row0;
  const unsigned short* inb = in + (((size_t)b*RBin + slot)*Wp + 1)*256;

  f32x4 acc[3];
  #pragma unroll
  for (int f=0;f<3;f++) acc[f] = (f32x4){0.f,0.f,0.f,0.f};

  for (int kc=0;kc<8;kc++){
    {
      int px = tid>>2, q = tid&3;
      int xg = x0+px;
      us4 v0={0,0,0,0}, v1={0,0,0,0};
      if (xg < W){
        const unsigned short* src = inb + (size_t)xg*256 + kc*32 + q*8;
        v0 = *(const us4*)src; v1 = *(const us4*)(src+4);
      }
      unsigned short* d = &Xs[px][q*8];
      *(us4*)d = v0; *(us4*)(d+4) = v1;
    }
    __syncthreads();
    bf16x8 Bf = *(const bf16x8*)&Xs[w*16 + l15][g4*8];
    #pragma unroll
    for (int f=0;f<3;f++){
      bf16x8 Af = *(const bf16x8*)(wfP + (((size_t)kc*3 + f)*64 + lane)*8);
      acc[f] = __builtin_amdgcn_mfma_f32_16x16x32_bf16(Af, Bf, acc[f], 0,0,0);
    }
    __syncthreads();
  }
  size_t S = (size_t)H*W;
  int px = x0 + w*16 + l15;
  if (px >= W) return;
  #pragma unroll
  for (int f=0;f<3;f++){
    #pragma unroll
    for (int r=0;r<4;r++){
      int co = f*16 + g4*4 + r;
      if (co < 45){
        float val = acc[f][r] + bp[co];
        int a_idx = co/15, c = co%15;
        int cum,c0,n;
        if (c<4)       {cum=0;c0=0;n=4;}
        else if (c==4) {cum=4;c0=4;n=1;}
        else if (c<10) {cum=5;c0=5;n=5;}
        else if (c<14) {cum=10;c0=10;n=4;}
        else           {cum=14;c0=14;n=1;}
        if (c==4) val = 1.f/(1.f+expf(-val));
        else if (c==14) val = (val>20.f? val : log1pf(expf(val))) + 1.f;
        size_t chan = ((size_t)(12*cum) + (size_t)((b*3+a_idx)*n + (c-c0)))*S;
        outl[chan + (size_t)y*W + px] = val;
      }
    }
  }
}

// ---------- host ----------
extern "C" void kernel_launch(void* const* d_in, const int* in_sizes, int n_in,
                              void* d_out, int out_size, void* d_ws, size_t ws_size,
                              hipStream_t stream)
{
  static const int Hs[4] = {192,96,48,24};
  static const int Wd[4] = {320,160,80,40};
  const float* feat[4] = {(const float*)d_in[0],(const float*)d_in[1],
                          (const float*)d_in[2],(const float*)d_in[3]};
  const float* adapt_w = (const float*)d_in[4];
  const float* adapt_b = (const float*)d_in[5];
  const float* w1 = (const float*)d_in[6];  const float* b1 = (const float*)d_in[7];
  const float* g1 = (const float*)d_in[8];  const float* be1= (const float*)d_in[9];
  const float* m1 = (const float*)d_in[10]; const float* v1 = (const float*)d_in[11];
  const float* w2 = (const float*)d_in[12]; const float* b2 = (const float*)d_in[13];
  const float* g2 = (const float*)d_in[14]; const float* be2= (const float*)d_in[15];
  const float* m2 = (const float*)d_in[16]; const float* v2 = (const float*)d_in[17];
  const float* wp = (const float*)d_in[18]; const float* bp = (const float*)d_in[19];
  float* out = (float*)d_out;

  char* base = (char*)d_ws;
  size_t off = 0;
  auto alloc = [&](size_t bytes)->char*{
    char* p = base + off; off = (off + bytes + 255) & ~(size_t)255; return p; };

  const size_t WF3_L = (size_t)16*8*9*512;
  const size_t WFA_L = (size_t)16*8*512;
  const size_t WFP_L = (size_t)8*3*512;
  unsigned short* wf1 = (unsigned short*)alloc(4*WF3_L*2);
  unsigned short* wf2 = (unsigned short*)alloc(4*WF3_L*2);
  unsigned short* wfA = (unsigned short*)alloc(4*WFA_L*2);
  unsigned short* wfP = (unsigned short*)alloc(4*WFP_L*2);
  float* biasc1 = (float*)alloc(1024*4);
  float* biasc2 = (float*)alloc(1024*4);
  char*  bufbase = base + off;
  size_t rem = (ws_size > off) ? (ws_size - off) : 0;

  k_repack_conv <<<dim3(1024), dim3(256), 0, stream>>>(w1, g1, v1, wf1);
  k_repack_conv <<<dim3(1024), dim3(256), 0, stream>>>(w2, g2, v2, wf2);
  k_repack_adapt<<<dim3(128),  dim3(256), 0, stream>>>(adapt_w, wfA);
  k_repack_pred <<<dim3(32),   dim3(192), 0, stream>>>(wp, wfP);
  k_bias<<<dim3(4), dim3(256), 0, stream>>>(b1, g1, be1, m1, v1, biasc1);
  k_bias<<<dim3(4), dim3(256), 0, stream>>>(b2, g2, be2, m2, v2, biasc2);

  size_t out_off = 0;
  for (int l=0;l<4;l++){
    int H = Hs[l], W = Wd[l], Wp = W + 2;
    size_t S = (size_t)H*W;
    size_t rowEl = (size_t)Wp*256;            // elements per slot per batch
    long rowsAvail = (long)((rem/2) / rowEl); // in slot-rows (single batch)
    long Rl = (rowsAvail - 46) / 12;
    int R = (int)(Rl < 1 ? 1 : (Rl > H ? (long)H : Rl));
    int RBf = R + 4, RB1 = R + 2;
    unsigned short* featT = (unsigned short*)bufbase;      // also conv2 output
    unsigned short* buf0  = featT + ((size_t)4*RBf + 2)*rowEl;
    unsigned short* buf1  = buf0  + ((size_t)4*RBf + 2)*rowEl;
    int nPxT = (W + 63) / 64;
    long zcGrid0 = ((long)4*RBf*2*256 + 2047)/2048;
    long zcGrid1 = ((long)4*RB1*2*256 + 2047)/2048;
    k_zcol<<<dim3((unsigned)zcGrid0), dim3(256), 0, stream>>>(buf0, Wp, RBf, W);
    k_zcol<<<dim3((unsigned)zcGrid1), dim3(256), 0, stream>>>(buf1, Wp, RB1, W);

    for (int r0 = 0; r0 < H; r0 += R){
      int r1 = (r0 + R < H) ? (r0 + R) : H;
      int Rc = r1 - r0;
      int ya0 = (r0-2 < 0) ? 0 : r0-2;
      int ya1 = (r1+2 > H) ? H : r1+2;
      int yb0 = (r0-1 < 0) ? 0 : r0-1;
      int yb1 = (r1+1 > H) ? H : r1+1;

      if (r0 == 0){
        long zg = ((long)4*2*Wp*256 + 2047)/2048;
        k_zrow<<<dim3((unsigned)zg), dim3(256), 0, stream>>>(buf0, (long)RBf*Wp*256, Wp, 0, 2);
        long zg1 = ((long)4*1*Wp*256 + 2047)/2048;
        k_zrow<<<dim3((unsigned)zg1), dim3(256), 0, stream>>>(buf1, (long)RB1*Wp*256, Wp, 0, 1);
      }
      if (r1 == H){
        long zg = ((long)4*2*Wp*256 + 2047)/2048;
        k_zrow<<<dim3((unsigned)zg), dim3(256), 0, stream>>>(buf0, (long)RBf*Wp*256, Wp, Rc+2, 2);
        long zg1 = ((long)4*1*Wp*256 + 2047)/2048;
        k_zrow<<<dim3((unsigned)zg1), dim3(256), 0, stream>>>(buf1, (long)RB1*Wp*256, Wp, Rc+1, 1);
      }

      k_trans<<<dim3(nPxT, ya1-ya0, 4), dim3(256), 0, stream>>>(
          feat[l], featT, H, W, Wp, ya0, ya0-(r0-2), RBf);

      // adapt: featT -> buf0, rows [ya0, ya1)
      k_conv2r<1,false><<<dim3(nPxT, (ya1-ya0+1)/2, 4), dim3(256), 0, stream>>>(
          featT, wfA + (size_t)l*WFA_L, adapt_b + l*256, buf0,
          W, Wp, ya0, ya1-ya0, r0-2, RBf, r0-2, RBf);

      // conv1: buf0 -> buf1, rows [yb0, yb1)
      k_conv2r<9,true><<<dim3(nPxT, (yb1-yb0+1)/2, 4), dim3(256), 0, stream>>>(
          buf0, wf1 + (size_t)l*WF3_L, biasc1 + l*256, buf1,
          W, Wp, yb0, yb1-yb0, r0-2, RBf, r0-1, RB1);

      // conv2: buf1 -> featT, rows [r0, r1)
      k_conv2r<9,true><<<dim3(nPxT, (Rc+1)/2, 4), dim3(256), 0, stream>>>(
          buf1, wf2 + (size_t)l*WF3_L, biasc2 + l*256, featT,
          W, Wp, r0, Rc, r0-1, RB1, r0, RBf);

      k_pred_mfma<<<dim3(nPxT, Rc, 4), dim3(256), 0, stream>>>(
          featT, wfP + (size_t)l*WFP_L, bp + l*45, out + out_off,
          H, W, Wp, r0, r0, RBf);
    }
    out_off += (size_t)4*45*S;
  }
}